// Round 1
// baseline (794.958 us; speedup 1.0000x reference)
//
#include <hip/hip_runtime.h>

#define DEVINL __device__ __forceinline__

typedef __bf16 bf16x8 __attribute__((ext_vector_type(8)));
typedef float f32x4 __attribute__((ext_vector_type(4)));
typedef unsigned short ushort8_t __attribute__((ext_vector_type(8)));

static constexpr int Bb = 4, S = 2048, H = 1024, NH = 16, DK = 64, FF = 4096;
static constexpr int Mrows = Bb * S; // 8192

DEVINL unsigned short f2bf(float f) {
    union { float f; unsigned u; } v; v.f = f;
    unsigned r = v.u + 0x7fffu + ((v.u >> 16) & 1u);
    return (unsigned short)(r >> 16);
}

DEVINL void gld16(const void* g, void* l) {
    auto gp = reinterpret_cast<const __attribute__((address_space(1))) unsigned*>(
        reinterpret_cast<unsigned long long>(g));
    auto lp = reinterpret_cast<__attribute__((address_space(3))) unsigned*>(
        (unsigned)reinterpret_cast<unsigned long long>(l));
    __builtin_amdgcn_global_load_lds(gp, lp, 16, 0, 0);
}

// ---------------- weight convert: f32 W[K][N] -> bf16 Wt[N][K] ----------------
__global__ __launch_bounds__(256)
void wcvt(const float* __restrict__ in, unsigned short* __restrict__ out, int K, int N) {
    __shared__ float t[32][33];
    int n0 = blockIdx.x * 32, k0 = blockIdx.y * 32;
    int tx = threadIdx.x, ty = threadIdx.y;
#pragma unroll
    for (int i = 0; i < 32; i += 8) t[ty + i][tx] = in[(size_t)(k0 + ty + i) * N + n0 + tx];
    __syncthreads();
#pragma unroll
    for (int i = 0; i < 32; i += 8) out[(size_t)(n0 + ty + i) * K + k0 + tx] = f2bf(t[tx][ty + i]);
}

// ---------------- LayerNorm: f32 row -> bf16 row ----------------
__global__ __launch_bounds__(256)
void ln_kernel(const float* __restrict__ x, const float* __restrict__ g,
               const float* __restrict__ be, unsigned short* __restrict__ y) {
    int row = blockIdx.x, tid = threadIdx.x;
    const float4 v = ((const float4*)(x + (size_t)row * H))[tid];
    float s = v.x + v.y + v.z + v.w;
    float ss = v.x * v.x + v.y * v.y + v.z * v.z + v.w * v.w;
#pragma unroll
    for (int m = 1; m < 64; m <<= 1) { s += __shfl_xor(s, m); ss += __shfl_xor(ss, m); }
    __shared__ float red[2][4];
    int lane = tid & 63, w = tid >> 6;
    if (lane == 0) { red[0][w] = s; red[1][w] = ss; }
    __syncthreads();
    s = red[0][0] + red[0][1] + red[0][2] + red[0][3];
    ss = red[1][0] + red[1][1] + red[1][2] + red[1][3];
    float mean = s * (1.f / H);
    float var = ss * (1.f / H) - mean * mean;
    float rstd = rsqrtf(var + 1e-5f);
    float4 gv = ((const float4*)g)[tid];
    float4 bv = ((const float4*)be)[tid];
    ushort4 o;
    o.x = f2bf((v.x - mean) * rstd * gv.x + bv.x);
    o.y = f2bf((v.y - mean) * rstd * gv.y + bv.y);
    o.z = f2bf((v.z - mean) * rstd * gv.z + bv.z);
    o.w = f2bf((v.w - mean) * rstd * gv.w + bv.w);
    ((ushort4*)(y + (size_t)row * H))[tid] = o;
}

// ---------------- GEMM: C[M,N] = A[M,K](bf16) @ Bt[N,K]^T(bf16) + bias ----------------
// EPI: 0 = store bf16, 1 = gelu->bf16, 2 = f32 + resid
template <int EPI>
__global__ __launch_bounds__(256)
void gemm_kernel(const unsigned short* __restrict__ A, const unsigned short* __restrict__ Bt,
                 const float* __restrict__ bias, const float* __restrict__ resid,
                 void* __restrict__ outp, int M, int N, int K) {
    __shared__ __align__(16) unsigned short lA[128 * 32];
    __shared__ __align__(16) unsigned short lB[128 * 32];
    const int tid = threadIdx.x;
    const int lane = tid & 63, w = tid >> 6;
    const int wr = w >> 1, wc = w & 1;
    const int m0 = blockIdx.x * 128, n0 = blockIdx.y * 128;
    const int fr = lane & 15, fq = lane >> 4;
    f32x4 acc[4][4] = {};

    const int srow = (w * 2) * 16 + (lane >> 2); // j=0 row within tile
    const int scol = (lane & 3) * 8;             // element offset within 32-col row
    const size_t abase = (size_t)(m0 + srow) * K + scol;
    const size_t bbase = (size_t)(n0 + srow) * K + scol;
    unsigned short* lA0 = &lA[(w * 2) * 16 * 32];
    unsigned short* lB0 = &lB[(w * 2) * 16 * 32];

    for (int k0 = 0; k0 < K; k0 += 32) {
        gld16(A + abase + k0, lA0);
        gld16(A + abase + (size_t)16 * K + k0, lA0 + 16 * 32);
        gld16(Bt + bbase + k0, lB0);
        gld16(Bt + bbase + (size_t)16 * K + k0, lB0 + 16 * 32);
        __syncthreads();
        bf16x8 af[4], bfr[4];
#pragma unroll
        for (int m = 0; m < 4; ++m) af[m] = *(const bf16x8*)&lA[(wr * 64 + m * 16 + fr) * 32 + fq * 8];
#pragma unroll
        for (int n = 0; n < 4; ++n) bfr[n] = *(const bf16x8*)&lB[(wc * 64 + n * 16 + fr) * 32 + fq * 8];
#pragma unroll
        for (int m = 0; m < 4; ++m)
#pragma unroll
            for (int n = 0; n < 4; ++n)
                acc[m][n] = __builtin_amdgcn_mfma_f32_16x16x32_bf16(af[m], bfr[n], acc[m][n], 0, 0, 0);
        __syncthreads();
    }

#pragma unroll
    for (int m = 0; m < 4; ++m) {
        int row0 = m0 + wr * 64 + m * 16 + fq * 4;
#pragma unroll
        for (int n = 0; n < 4; ++n) {
            int col = n0 + wc * 64 + n * 16 + fr;
            float bz = bias[col];
#pragma unroll
            for (int j = 0; j < 4; ++j) {
                float vv = acc[m][n][j] + bz;
                size_t idx = (size_t)(row0 + j) * N + col;
                if (EPI == 0) {
                    ((unsigned short*)outp)[idx] = f2bf(vv);
                } else if (EPI == 1) {
                    float t = 0.5f * vv * (1.f + erff(vv * 0.70710678118654752f));
                    ((unsigned short*)outp)[idx] = f2bf(t);
                } else {
                    ((float*)outp)[idx] = vv + resid[idx];
                }
            }
        }
    }
}

// ---------------- flash attention with additive bias ----------------
__global__ __launch_bounds__(256)
void attn_kernel(const unsigned short* __restrict__ Q, const unsigned short* __restrict__ Kb,
                 const unsigned short* __restrict__ V, const float* __restrict__ bias,
                 unsigned short* __restrict__ O) {
    __shared__ __align__(16) unsigned short lK[64 * 64];
    __shared__ __align__(16) unsigned short lV[64 * 64];
    __shared__ __align__(16) unsigned short lP[4][16 * 64];
    const int tid = threadIdx.x, lane = tid & 63, w = tid >> 6;
    const int fr = lane & 15, fq = lane >> 4;
    const int q0 = blockIdx.x * 64, h = blockIdx.y, b = blockIdx.z;
    const size_t base = ((size_t)b * S) * H + h * DK;

    bf16x8 aq[2];
    {
        const unsigned short* qp = Q + base + (size_t)(q0 + w * 16 + fr) * H + fq * 8;
        aq[0] = *(const bf16x8*)qp;
        aq[1] = *(const bf16x8*)(qp + 32);
    }
    f32x4 oacc[4] = {};
    float mrun[4], lrun[4];
#pragma unroll
    for (int j = 0; j < 4; ++j) { mrun[j] = -3e38f; lrun[j] = 0.f; }
    const float* bias_r[4];
#pragma unroll
    for (int j = 0; j < 4; ++j)
        bias_r[j] = bias + (size_t)h * S * S + (size_t)(q0 + w * 16 + fq * 4 + j) * S;

    const int srow = tid >> 3;        // 0..31
    const int sbyte = (tid & 7) * 16; // byte offset in 128B row (K staging)
    const int sd0 = (tid & 7) * 8;    // d start (V staging)

    for (int kt = 0; kt < S / 64; ++kt) {
        const int k0 = kt * 64;
        __syncthreads();
#pragma unroll
        for (int p = 0; p < 2; ++p) {
            int r = srow + p * 32;
            ushort8_t kval = *(const ushort8_t*)(Kb + base + (size_t)(k0 + r) * H + sbyte / 2);
            *(ushort8_t*)((char*)lK + ((r * 128 + sbyte) ^ ((r & 7) << 4))) = kval;
            ushort8_t vval = *(const ushort8_t*)(V + base + (size_t)(k0 + r) * H + sd0);
#pragma unroll
            for (int e = 0; e < 8; ++e) {
                int d = sd0 + e;
                *(unsigned short*)((char*)lV + ((d * 128 + r * 2) ^ ((d & 7) << 4))) = vval[e];
            }
        }
        __syncthreads();

        // S = Q K^T
        f32x4 sacc[4] = {};
#pragma unroll
        for (int c = 0; c < 4; ++c) {
            int row = c * 16 + fr;
#pragma unroll
            for (int dh = 0; dh < 2; ++dh) {
                bf16x8 bk = *(const bf16x8*)((char*)lK + ((row * 128 + dh * 64 + fq * 16) ^ ((row & 7) << 4)));
                sacc[c] = __builtin_amdgcn_mfma_f32_16x16x32_bf16(aq[dh], bk, sacc[c], 0, 0, 0);
            }
        }

        // online softmax
        float sb[4][4];
        float tmax[4] = {-3e38f, -3e38f, -3e38f, -3e38f};
#pragma unroll
        for (int c = 0; c < 4; ++c) {
            int kc = k0 + c * 16 + fr;
#pragma unroll
            for (int j = 0; j < 4; ++j) {
                float sv = sacc[c][j] * 0.125f + bias_r[j][kc];
                sb[c][j] = sv;
                tmax[j] = fmaxf(tmax[j], sv);
            }
        }
#pragma unroll
        for (int j = 0; j < 4; ++j)
#pragma unroll
            for (int m = 1; m < 16; m <<= 1) tmax[j] = fmaxf(tmax[j], __shfl_xor(tmax[j], m));
        float sf[4], rs[4];
#pragma unroll
        for (int j = 0; j < 4; ++j) {
            float mnew = fmaxf(mrun[j], tmax[j]);
            sf[j] = expf(mrun[j] - mnew);
            mrun[j] = mnew;
            rs[j] = 0.f;
        }
#pragma unroll
        for (int c = 0; c < 4; ++c)
#pragma unroll
            for (int j = 0; j < 4; ++j) {
                float p = expf(sb[c][j] - mrun[j]);
                rs[j] += p;
                int prow = fq * 4 + j;
                *(unsigned short*)((char*)&lP[w][0] + ((prow * 128 + (c * 16 + fr) * 2) ^ ((prow & 7) << 4))) = f2bf(p);
            }
#pragma unroll
        for (int j = 0; j < 4; ++j) {
#pragma unroll
            for (int m = 1; m < 16; m <<= 1) rs[j] += __shfl_xor(rs[j], m);
            lrun[j] = lrun[j] * sf[j] + rs[j];
        }
#pragma unroll
        for (int c = 0; c < 4; ++c)
#pragma unroll
            for (int j = 0; j < 4; ++j) oacc[c][j] *= sf[j];

        // O += P V
#pragma unroll
        for (int ks = 0; ks < 2; ++ks) {
            bf16x8 pa = *(const bf16x8*)((char*)&lP[w][0] + ((fr * 128 + ks * 64 + fq * 16) ^ ((fr & 7) << 4)));
#pragma unroll
            for (int c = 0; c < 4; ++c) {
                int vr = c * 16 + fr;
                bf16x8 bv = *(const bf16x8*)((char*)lV + ((vr * 128 + ks * 64 + fq * 16) ^ ((vr & 7) << 4)));
                oacc[c] = __builtin_amdgcn_mfma_f32_16x16x32_bf16(pa, bv, oacc[c], 0, 0, 0);
            }
        }
    }

#pragma unroll
    for (int c = 0; c < 4; ++c)
#pragma unroll
        for (int j = 0; j < 4; ++j) {
            int row = q0 + w * 16 + fq * 4 + j;
            int d = c * 16 + fr;
            O[base + (size_t)row * H + d] = f2bf(oacc[c][j] / lrun[j]);
        }
}

extern "C" void kernel_launch(void* const* d_in, const int* in_sizes, int n_in,
                              void* d_out, int out_size, void* d_ws, size_t ws_size,
                              hipStream_t stream) {
    const float* x    = (const float*)d_in[0];
    const float* ab   = (const float*)d_in[1];
    const float* ln1g = (const float*)d_in[2];
    const float* ln1b = (const float*)d_in[3];
    const float* Wq   = (const float*)d_in[4];
    const float* bq   = (const float*)d_in[5];
    const float* Wk   = (const float*)d_in[6];
    const float* bk   = (const float*)d_in[7];
    const float* Wv   = (const float*)d_in[8];
    const float* bv   = (const float*)d_in[9];
    const float* Wo   = (const float*)d_in[10];
    const float* bo   = (const float*)d_in[11];
    const float* ln2g = (const float*)d_in[12];
    const float* ln2b = (const float*)d_in[13];
    const float* W1   = (const float*)d_in[14];
    const float* b1   = (const float*)d_in[15];
    const float* W2   = (const float*)d_in[16];
    const float* b2   = (const float*)d_in[17];

    char* ws = (char*)d_ws;
    size_t off = 0;
    auto alloc = [&](size_t bytes) -> void* {
        void* p = ws + off;
        off += (bytes + 255) & ~(size_t)255;
        return p;
    };
    unsigned short* Wqt = (unsigned short*)alloc((size_t)H * H * 2);
    unsigned short* Wkt = (unsigned short*)alloc((size_t)H * H * 2);
    unsigned short* Wvt = (unsigned short*)alloc((size_t)H * H * 2);
    unsigned short* Wot = (unsigned short*)alloc((size_t)H * H * 2);
    unsigned short* W1t = (unsigned short*)alloc((size_t)H * FF * 2);
    unsigned short* W2t = (unsigned short*)alloc((size_t)H * FF * 2);
    unsigned short* ybuf = (unsigned short*)alloc((size_t)Mrows * H * 2);
    unsigned short* qb = (unsigned short*)alloc((size_t)Mrows * H * 2);
    unsigned short* kb = (unsigned short*)alloc((size_t)Mrows * H * 2);
    unsigned short* vb = (unsigned short*)alloc((size_t)Mrows * H * 2);
    unsigned short* ob = (unsigned short*)alloc((size_t)Mrows * H * 2);
    unsigned short* hb = (unsigned short*)alloc((size_t)Mrows * FF * 2);
    (void)ws_size; (void)in_sizes; (void)n_in; (void)out_size;

    dim3 tb(32, 8, 1);
    wcvt<<<dim3(H / 32, H / 32), tb, 0, stream>>>(Wq, Wqt, H, H);
    wcvt<<<dim3(H / 32, H / 32), tb, 0, stream>>>(Wk, Wkt, H, H);
    wcvt<<<dim3(H / 32, H / 32), tb, 0, stream>>>(Wv, Wvt, H, H);
    wcvt<<<dim3(H / 32, H / 32), tb, 0, stream>>>(Wo, Wot, H, H);
    wcvt<<<dim3(FF / 32, H / 32), tb, 0, stream>>>(W1, W1t, H, FF);
    wcvt<<<dim3(H / 32, FF / 32), tb, 0, stream>>>(W2, W2t, FF, H);

    ln_kernel<<<Mrows, 256, 0, stream>>>(x, ln1g, ln1b, ybuf);

    gemm_kernel<0><<<dim3(Mrows / 128, H / 128), 256, 0, stream>>>(ybuf, Wqt, bq, nullptr, qb, Mrows, H, H);
    gemm_kernel<0><<<dim3(Mrows / 128, H / 128), 256, 0, stream>>>(ybuf, Wkt, bk, nullptr, kb, Mrows, H, H);
    gemm_kernel<0><<<dim3(Mrows / 128, H / 128), 256, 0, stream>>>(ybuf, Wvt, bv, nullptr, vb, Mrows, H, H);

    attn_kernel<<<dim3(S / 64, NH, Bb), 256, 0, stream>>>(qb, kb, vb, ab, ob);

    gemm_kernel<2><<<dim3(Mrows / 128, H / 128), 256, 0, stream>>>(ob, Wot, bo, x, d_out, Mrows, H, H);

    ln_kernel<<<Mrows, 256, 0, stream>>>((const float*)d_out, ln2g, ln2b, ybuf);

    gemm_kernel<1><<<dim3(Mrows / 128, FF / 128), 256, 0, stream>>>(ybuf, W1t, b1, nullptr, hb, Mrows, FF, H);
    gemm_kernel<2><<<dim3(Mrows / 128, H / 128), 256, 0, stream>>>(hb, W2t, b2, (const float*)d_out, d_out, Mrows, H, FF);
}

// Round 3
// 652.087 us; speedup vs baseline: 1.2191x; 1.2191x over previous
//
#include <hip/hip_runtime.h>

#define DEVINL __device__ __forceinline__

typedef __bf16 bf16x8 __attribute__((ext_vector_type(8)));
typedef float f32x4 __attribute__((ext_vector_type(4)));
typedef unsigned short ushort8_t __attribute__((ext_vector_type(8)));
typedef unsigned short u16x4 __attribute__((ext_vector_type(4)));

static constexpr int Bb = 4, S = 2048, H = 1024, NH = 16, DK = 64, FF = 4096;
static constexpr int Mrows = Bb * S; // 8192
static constexpr int QS = 3 * H;    // fused QKV row stride

DEVINL unsigned short f2bf(float f) {
    union { float f; unsigned u; } v; v.f = f;
    unsigned r = v.u + 0x7fffu + ((v.u >> 16) & 1u);
    return (unsigned short)(r >> 16);
}

DEVINL void gld16(const void* g, void* l) {
    auto gp = reinterpret_cast<const __attribute__((address_space(1))) unsigned*>(
        reinterpret_cast<unsigned long long>(g));
    auto lp = reinterpret_cast<__attribute__((address_space(3))) unsigned*>(
        (unsigned)reinterpret_cast<unsigned long long>(l));
    __builtin_amdgcn_global_load_lds(gp, lp, 16, 0, 0);
}

// ---------------- weight convert: f32 W[K][N] -> bf16 Wt[N][K] ----------------
__global__ __launch_bounds__(256)
void wcvt(const float* __restrict__ in, unsigned short* __restrict__ out, int K, int N) {
    __shared__ float t[32][33];
    int n0 = blockIdx.x * 32, k0 = blockIdx.y * 32;
    int tx = threadIdx.x, ty = threadIdx.y;
#pragma unroll
    for (int i = 0; i < 32; i += 8) t[ty + i][tx] = in[(size_t)(k0 + ty + i) * N + n0 + tx];
    __syncthreads();
#pragma unroll
    for (int i = 0; i < 32; i += 8) out[(size_t)(n0 + ty + i) * K + k0 + tx] = f2bf(t[tx][ty + i]);
}

// ---------------- fuse q/k/v bias into one [3072] array ----------------
__global__ __launch_bounds__(256)
void catbias(const float* __restrict__ a, const float* __restrict__ b,
             const float* __restrict__ c, float* __restrict__ o) {
    int i = blockIdx.x * 256 + threadIdx.x;
    float v = (i < 1024) ? a[i] : (i < 2048 ? b[i - 1024] : c[i - 2048]);
    o[i] = v;
}

// ---------------- LayerNorm: f32 row -> bf16 row ----------------
__global__ __launch_bounds__(256)
void ln_kernel(const float* __restrict__ x, const float* __restrict__ g,
               const float* __restrict__ be, unsigned short* __restrict__ y) {
    int row = blockIdx.x, tid = threadIdx.x;
    const float4 v = ((const float4*)(x + (size_t)row * H))[tid];
    float s = v.x + v.y + v.z + v.w;
    float ss = v.x * v.x + v.y * v.y + v.z * v.z + v.w * v.w;
#pragma unroll
    for (int m = 1; m < 64; m <<= 1) { s += __shfl_xor(s, m); ss += __shfl_xor(ss, m); }
    __shared__ float red[2][4];
    int lane = tid & 63, w = tid >> 6;
    if (lane == 0) { red[0][w] = s; red[1][w] = ss; }
    __syncthreads();
    s = red[0][0] + red[0][1] + red[0][2] + red[0][3];
    ss = red[1][0] + red[1][1] + red[1][2] + red[1][3];
    float mean = s * (1.f / H);
    float var = ss * (1.f / H) - mean * mean;
    float rstd = rsqrtf(var + 1e-5f);
    float4 gv = ((const float4*)g)[tid];
    float4 bv = ((const float4*)be)[tid];
    ushort4 o;
    o.x = f2bf((v.x - mean) * rstd * gv.x + bv.x);
    o.y = f2bf((v.y - mean) * rstd * gv.y + bv.y);
    o.z = f2bf((v.z - mean) * rstd * gv.z + bv.z);
    o.w = f2bf((v.w - mean) * rstd * gv.w + bv.w);
    ((ushort4*)(y + (size_t)row * H))[tid] = o;
}

// ---------------- GEMM: C[M,N] = A[M,K](bf16) @ Bt[N,K]^T(bf16) + bias ----------------
// EPI: 0 = store bf16, 1 = gelu->bf16, 2 = f32 + resid
template <int EPI>
__global__ __launch_bounds__(256)
void gemm_kernel(const unsigned short* __restrict__ A, const unsigned short* __restrict__ Bt,
                 const float* __restrict__ bias, const float* __restrict__ resid,
                 void* __restrict__ outp, int M, int N, int K) {
    __shared__ __align__(16) unsigned short lA[128 * 32];
    __shared__ __align__(16) unsigned short lB[128 * 32];
    const int tid = threadIdx.x;
    const int lane = tid & 63, w = tid >> 6;
    const int wr = w >> 1, wc = w & 1;
    const int m0 = blockIdx.x * 128, n0 = blockIdx.y * 128;
    const int fr = lane & 15, fq = lane >> 4;
    f32x4 acc[4][4] = {};

    const int srow = (w * 2) * 16 + (lane >> 2);
    const int scol = (lane & 3) * 8;
    const size_t abase = (size_t)(m0 + srow) * K + scol;
    const size_t bbase = (size_t)(n0 + srow) * K + scol;
    unsigned short* lA0 = &lA[(w * 2) * 16 * 32];
    unsigned short* lB0 = &lB[(w * 2) * 16 * 32];

    for (int k0 = 0; k0 < K; k0 += 32) {
        gld16(A + abase + k0, lA0);
        gld16(A + abase + (size_t)16 * K + k0, lA0 + 16 * 32);
        gld16(Bt + bbase + k0, lB0);
        gld16(Bt + bbase + (size_t)16 * K + k0, lB0 + 16 * 32);
        __syncthreads();
        bf16x8 af[4], bfr[4];
#pragma unroll
        for (int m = 0; m < 4; ++m) af[m] = *(const bf16x8*)&lA[(wr * 64 + m * 16 + fr) * 32 + fq * 8];
#pragma unroll
        for (int n = 0; n < 4; ++n) bfr[n] = *(const bf16x8*)&lB[(wc * 64 + n * 16 + fr) * 32 + fq * 8];
#pragma unroll
        for (int m = 0; m < 4; ++m)
#pragma unroll
            for (int n = 0; n < 4; ++n)
                acc[m][n] = __builtin_amdgcn_mfma_f32_16x16x32_bf16(af[m], bfr[n], acc[m][n], 0, 0, 0);
        __syncthreads();
    }

#pragma unroll
    for (int m = 0; m < 4; ++m) {
        int row0 = m0 + wr * 64 + m * 16 + fq * 4;
#pragma unroll
        for (int n = 0; n < 4; ++n) {
            int col = n0 + wc * 64 + n * 16 + fr;
            float bz = bias[col];
#pragma unroll
            for (int j = 0; j < 4; ++j) {
                float vv = acc[m][n][j] + bz;
                size_t idx = (size_t)(row0 + j) * N + col;
                if (EPI == 0) {
                    ((unsigned short*)outp)[idx] = f2bf(vv);
                } else if (EPI == 1) {
                    float t = 0.5f * vv * (1.f + erff(vv * 0.70710678118654752f));
                    ((unsigned short*)outp)[idx] = f2bf(t);
                } else {
                    ((float*)outp)[idx] = vv + resid[idx];
                }
            }
        }
    }
}

// ---------------- flash attention with additive bias ----------------
// QKV fused input [Mrows][3072]; K LDS row-major+XOR-swizzle via pre-swizzled
// gld16 source; V LDS in 4x16 subtiles for ds_read_b64_tr_b16 consumption.
__global__ __launch_bounds__(256)
void attn_kernel(const unsigned short* __restrict__ QKV, const float* __restrict__ bias,
                 unsigned short* __restrict__ O) {
    __shared__ __align__(16) unsigned short lK[2][4096];
    __shared__ __align__(16) unsigned short lV[2][4096];
    __shared__ __align__(16) unsigned short lP[4][16 * 64];
    const int tid = threadIdx.x, lane = tid & 63, w = tid >> 6;
    const int fr = lane & 15, fq = lane >> 4;
    const int b = blockIdx.x, h = blockIdx.y, q0 = blockIdx.z * 64;
    const size_t base = (size_t)b * S * QS + h * DK;
    const unsigned short* Qp = QKV + base;
    const unsigned short* Kp = QKV + base + H;
    const unsigned short* Vp = QKV + base + 2 * H;
    const size_t obase = (size_t)b * S * H + h * DK;

    // Q fragments (registers, whole kernel)
    bf16x8 aq[2];
    {
        const unsigned short* qp = Qp + (size_t)(q0 + w * 16 + fr) * QS + fq * 8;
        aq[0] = *(const bf16x8*)qp;
        aq[1] = *(const bf16x8*)(qp + 32);
    }

    // staging source coords (per thread, chunk = 16B = 8 elems)
    // K: row-major [64][64] with 16B-chunk XOR swizzle folded into the source
    const int chk0 = w * 128 + lane, chk1 = chk0 + 64;
    const int rK0 = chk0 >> 3, cK0 = ((chk0 & 7) ^ (rK0 & 7)) * 8;
    const int rK1 = chk1 >> 3, cK1 = ((chk1 & 7) ^ (rK1 & 7)) * 8;
    // V: subtiled layout: E(k,d) = ks*2048 + c*512 + half*256 + fq*64 + j*16 + dc
    //    with k = ks*32 + fq*8 + half*4 + j, d = c*16 + dc
    int vk0, vd0, vk1, vd1;
    {
        int ch = chk0;
        int dch = ch & 1, j = (ch >> 1) & 3, fqi = (ch >> 3) & 3, half = (ch >> 5) & 1,
            c = (ch >> 6) & 3, ks = (ch >> 8) & 1;
        vk0 = ks * 32 + fqi * 8 + half * 4 + j; vd0 = c * 16 + dch * 8;
        ch = chk1;
        dch = ch & 1; j = (ch >> 1) & 3; fqi = (ch >> 3) & 3; half = (ch >> 5) & 1;
        c = (ch >> 6) & 3; ks = (ch >> 8) & 1;
        vk1 = ks * 32 + fqi * 8 + half * 4 + j; vd1 = c * 16 + dch * 8;
    }

    f32x4 oacc[4] = {};
    float mrun[4], lrun[4];
#pragma unroll
    for (int j = 0; j < 4; ++j) { mrun[j] = -3e38f; lrun[j] = 0.f; }
    const float* bias_r[4];
#pragma unroll
    for (int j = 0; j < 4; ++j)
        bias_r[j] = bias + (size_t)h * S * S + (size_t)(q0 + w * 16 + fq * 4 + j) * S;

    auto stage = [&](int buf, int k0) {
        gld16(Kp + (size_t)(k0 + rK0) * QS + cK0, &lK[buf][w * 1024]);
        gld16(Kp + (size_t)(k0 + rK1) * QS + cK1, &lK[buf][w * 1024 + 512]);
        gld16(Vp + (size_t)(k0 + vk0) * QS + vd0, &lV[buf][w * 1024]);
        gld16(Vp + (size_t)(k0 + vk1) * QS + vd1, &lV[buf][w * 1024 + 512]);
    };

    stage(0, 0);
    int cur = 0;
    for (int kt = 0; kt < S / 64; ++kt) {
        const int k0 = kt * 64;
        __syncthreads(); // drains vmcnt(0): buf[cur] ready; prev reads of buf[cur^1] done
        if (kt + 1 < S / 64) stage(cur ^ 1, k0 + 64);

        // bias for this tile into registers (gives the loads latency room)
        float bvreg[4][4];
#pragma unroll
        for (int c = 0; c < 4; ++c)
#pragma unroll
            for (int j = 0; j < 4; ++j) bvreg[c][j] = bias_r[j][k0 + c * 16 + fr];

        // S = Q K^T
        f32x4 sacc[4] = {};
        __builtin_amdgcn_s_setprio(1);
#pragma unroll
        for (int c = 0; c < 4; ++c) {
            int row = c * 16 + fr;
#pragma unroll
            for (int dh = 0; dh < 2; ++dh) {
                bf16x8 bk = *(const bf16x8*)((char*)lK[cur] +
                    ((row * 128 + dh * 64 + fq * 16) ^ ((row & 7) << 4)));
                sacc[c] = __builtin_amdgcn_mfma_f32_16x16x32_bf16(aq[dh], bk, sacc[c], 0, 0, 0);
            }
        }
        __builtin_amdgcn_s_setprio(0);

        // online softmax
        float sb[4][4];
        float tmax[4] = {-3e38f, -3e38f, -3e38f, -3e38f};
#pragma unroll
        for (int c = 0; c < 4; ++c)
#pragma unroll
            for (int j = 0; j < 4; ++j) {
                float sv = sacc[c][j] * 0.125f + bvreg[c][j];
                sb[c][j] = sv;
                tmax[j] = fmaxf(tmax[j], sv);
            }
#pragma unroll
        for (int j = 0; j < 4; ++j)
#pragma unroll
            for (int m = 1; m < 16; m <<= 1) tmax[j] = fmaxf(tmax[j], __shfl_xor(tmax[j], m));
        float sf[4], rs[4];
#pragma unroll
        for (int j = 0; j < 4; ++j) {
            float mnew = fmaxf(mrun[j], tmax[j]);
            sf[j] = __expf(mrun[j] - mnew);
            mrun[j] = mnew;
            rs[j] = 0.f;
        }
#pragma unroll
        for (int c = 0; c < 4; ++c)
#pragma unroll
            for (int j = 0; j < 4; ++j) {
                float p = __expf(sb[c][j] - mrun[j]);
                rs[j] += p;
                int prow = fq * 4 + j;
                *(unsigned short*)((char*)&lP[w][0] +
                    ((prow * 128 + (c * 16 + fr) * 2) ^ ((prow & 7) << 4))) = f2bf(p);
            }
#pragma unroll
        for (int j = 0; j < 4; ++j) {
#pragma unroll
            for (int m = 1; m < 16; m <<= 1) rs[j] += __shfl_xor(rs[j], m);
            lrun[j] = lrun[j] * sf[j] + rs[j];
        }
#pragma unroll
        for (int c = 0; c < 4; ++c)
#pragma unroll
            for (int j = 0; j < 4; ++j) oacc[c][j] *= sf[j];

        // O += P V   (V via HW transpose reads; per-lane addr = base + lane*8B)
#pragma unroll
        for (int ks = 0; ks < 2; ++ks) {
            bf16x8 pa = *(const bf16x8*)((char*)&lP[w][0] +
                ((fr * 128 + ks * 64 + fq * 16) ^ ((fr & 7) << 4)));
            const char* vb8 = (const char*)lV[cur] + ks * 4096;
            u16x4 ra[4], rb[4];
#pragma unroll
            for (int c = 0; c < 4; ++c) {
                unsigned ad = (unsigned)(unsigned long long)(vb8 + c * 1024) + lane * 8;
                asm volatile("ds_read_b64_tr_b16 %0, %1" : "=&v"(ra[c]) : "v"(ad));
                asm volatile("ds_read_b64_tr_b16 %0, %1 offset:512" : "=&v"(rb[c]) : "v"(ad));
            }
            asm volatile("s_waitcnt lgkmcnt(0)" ::: "memory");
            __builtin_amdgcn_sched_barrier(0);
            __builtin_amdgcn_s_setprio(1);
#pragma unroll
            for (int c = 0; c < 4; ++c) {
                union { u16x4 h2[2]; bf16x8 v8; } u;
                u.h2[0] = ra[c]; u.h2[1] = rb[c];
                oacc[c] = __builtin_amdgcn_mfma_f32_16x16x32_bf16(pa, u.v8, oacc[c], 0, 0, 0);
            }
            __builtin_amdgcn_s_setprio(0);
        }
        cur ^= 1;
    }

#pragma unroll
    for (int c = 0; c < 4; ++c)
#pragma unroll
        for (int j = 0; j < 4; ++j) {
            int row = q0 + w * 16 + fq * 4 + j;
            int d = c * 16 + fr;
            O[obase + (size_t)row * H + d] = f2bf(oacc[c][j] / lrun[j]);
        }
}

extern "C" void kernel_launch(void* const* d_in, const int* in_sizes, int n_in,
                              void* d_out, int out_size, void* d_ws, size_t ws_size,
                              hipStream_t stream) {
    const float* x    = (const float*)d_in[0];
    const float* ab   = (const float*)d_in[1];
    const float* ln1g = (const float*)d_in[2];
    const float* ln1b = (const float*)d_in[3];
    const float* Wq   = (const float*)d_in[4];
    const float* bq   = (const float*)d_in[5];
    const float* Wk   = (const float*)d_in[6];
    const float* bk   = (const float*)d_in[7];
    const float* Wv   = (const float*)d_in[8];
    const float* bv   = (const float*)d_in[9];
    const float* Wo   = (const float*)d_in[10];
    const float* bo   = (const float*)d_in[11];
    const float* ln2g = (const float*)d_in[12];
    const float* ln2b = (const float*)d_in[13];
    const float* W1   = (const float*)d_in[14];
    const float* b1   = (const float*)d_in[15];
    const float* W2   = (const float*)d_in[16];
    const float* b2   = (const float*)d_in[17];

    char* ws = (char*)d_ws;
    size_t off = 0;
    auto alloc = [&](size_t bytes) -> void* {
        void* p = ws + off;
        off += (bytes + 255) & ~(size_t)255;
        return p;
    };
    unsigned short* Wqt = (unsigned short*)alloc((size_t)H * H * 2); // contiguous q,k,v
    unsigned short* Wkt = (unsigned short*)alloc((size_t)H * H * 2);
    unsigned short* Wvt = (unsigned short*)alloc((size_t)H * H * 2);
    unsigned short* Wot = (unsigned short*)alloc((size_t)H * H * 2);
    unsigned short* W1t = (unsigned short*)alloc((size_t)H * FF * 2);
    unsigned short* W2t = (unsigned short*)alloc((size_t)H * FF * 2);
    float* bqkv        = (float*)alloc((size_t)QS * 4);
    unsigned short* ybuf = (unsigned short*)alloc((size_t)Mrows * H * 2);
    unsigned short* qkvb = (unsigned short*)alloc((size_t)Mrows * QS * 2);
    unsigned short* ob = (unsigned short*)alloc((size_t)Mrows * H * 2);
    unsigned short* hb = (unsigned short*)alloc((size_t)Mrows * FF * 2);
    (void)ws_size; (void)in_sizes; (void)n_in; (void)out_size;

    dim3 tb(32, 8, 1);
    wcvt<<<dim3(H / 32, H / 32), tb, 0, stream>>>(Wq, Wqt, H, H);
    wcvt<<<dim3(H / 32, H / 32), tb, 0, stream>>>(Wk, Wkt, H, H);
    wcvt<<<dim3(H / 32, H / 32), tb, 0, stream>>>(Wv, Wvt, H, H);
    wcvt<<<dim3(H / 32, H / 32), tb, 0, stream>>>(Wo, Wot, H, H);
    wcvt<<<dim3(FF / 32, H / 32), tb, 0, stream>>>(W1, W1t, H, FF);
    wcvt<<<dim3(H / 32, FF / 32), tb, 0, stream>>>(W2, W2t, FF, H);
    catbias<<<QS / 256, 256, 0, stream>>>(bq, bk, bv, bqkv);

    ln_kernel<<<Mrows, 256, 0, stream>>>(x, ln1g, ln1b, ybuf);

    // fused QKV projection: [8192,1024] @ [1024,3072]
    gemm_kernel<0><<<dim3(Mrows / 128, QS / 128), 256, 0, stream>>>(ybuf, Wqt, bqkv, nullptr, qkvb, Mrows, QS, H);

    attn_kernel<<<dim3(Bb, NH, S / 64), 256, 0, stream>>>(qkvb, ab, ob);

    gemm_kernel<2><<<dim3(Mrows / 128, H / 128), 256, 0, stream>>>(ob, Wot, bo, x, d_out, Mrows, H, H);

    ln_kernel<<<Mrows, 256, 0, stream>>>((const float*)d_out, ln2g, ln2b, ybuf);

    gemm_kernel<1><<<dim3(Mrows / 128, FF / 128), 256, 0, stream>>>(ybuf, W1t, b1, nullptr, hb, Mrows, FF, H);
    gemm_kernel<2><<<dim3(Mrows / 128, H / 128), 256, 0, stream>>>(hb, W2t, b2, (const float*)d_out, d_out, Mrows, H, FF);
}

// Round 4
// 643.365 us; speedup vs baseline: 1.2356x; 1.0136x over previous
//
#include <hip/hip_runtime.h>

#define DEVINL __device__ __forceinline__

typedef __bf16 bf16x8 __attribute__((ext_vector_type(8)));
typedef float f32x4 __attribute__((ext_vector_type(4)));
typedef unsigned short ushort8_t __attribute__((ext_vector_type(8)));
typedef unsigned short u16x4 __attribute__((ext_vector_type(4)));

static constexpr int Bb = 4, S = 2048, H = 1024, NH = 16, DK = 64, FF = 4096;
static constexpr int Mrows = Bb * S; // 8192
static constexpr int QS = 3 * H;    // fused QKV row stride

DEVINL unsigned short f2bf(float f) {
    union { __bf16 b; unsigned short u; } r;
    r.b = (__bf16)f;
    return r.u;
}

DEVINL void gld16(const void* g, void* l) {
    auto gp = reinterpret_cast<const __attribute__((address_space(1))) unsigned*>(
        reinterpret_cast<unsigned long long>(g));
    auto lp = reinterpret_cast<__attribute__((address_space(3))) unsigned*>(
        (unsigned)reinterpret_cast<unsigned long long>(l));
    __builtin_amdgcn_global_load_lds(gp, lp, 16, 0, 0);
}

// ---------------- weight convert: f32 W[K][N] -> bf16 Wt[N][K] ----------------
__global__ __launch_bounds__(256)
void wcvt(const float* __restrict__ in, unsigned short* __restrict__ out, int K, int N) {
    __shared__ float t[32][33];
    int n0 = blockIdx.x * 32, k0 = blockIdx.y * 32;
    int tx = threadIdx.x, ty = threadIdx.y;
#pragma unroll
    for (int i = 0; i < 32; i += 8) t[ty + i][tx] = in[(size_t)(k0 + ty + i) * N + n0 + tx];
    __syncthreads();
#pragma unroll
    for (int i = 0; i < 32; i += 8) out[(size_t)(n0 + ty + i) * K + k0 + tx] = f2bf(t[tx][ty + i]);
}

// ---------------- fuse q/k/v bias into one [3072] array ----------------
__global__ __launch_bounds__(256)
void catbias(const float* __restrict__ a, const float* __restrict__ b,
             const float* __restrict__ c, float* __restrict__ o) {
    int i = blockIdx.x * 256 + threadIdx.x;
    float v = (i < 1024) ? a[i] : (i < 2048 ? b[i - 1024] : c[i - 2048]);
    o[i] = v;
}

// ---------------- LayerNorm: f32 row -> bf16 row ----------------
__global__ __launch_bounds__(256)
void ln_kernel(const float* __restrict__ x, const float* __restrict__ g,
               const float* __restrict__ be, unsigned short* __restrict__ y) {
    int row = blockIdx.x, tid = threadIdx.x;
    const float4 v = ((const float4*)(x + (size_t)row * H))[tid];
    float s = v.x + v.y + v.z + v.w;
    float ss = v.x * v.x + v.y * v.y + v.z * v.z + v.w * v.w;
#pragma unroll
    for (int m = 1; m < 64; m <<= 1) { s += __shfl_xor(s, m); ss += __shfl_xor(ss, m); }
    __shared__ float red[2][4];
    int lane = tid & 63, w = tid >> 6;
    if (lane == 0) { red[0][w] = s; red[1][w] = ss; }
    __syncthreads();
    s = red[0][0] + red[0][1] + red[0][2] + red[0][3];
    ss = red[1][0] + red[1][1] + red[1][2] + red[1][3];
    float mean = s * (1.f / H);
    float var = ss * (1.f / H) - mean * mean;
    float rstd = rsqrtf(var + 1e-5f);
    float4 gv = ((const float4*)g)[tid];
    float4 bv = ((const float4*)be)[tid];
    ushort4 o;
    o.x = f2bf((v.x - mean) * rstd * gv.x + bv.x);
    o.y = f2bf((v.y - mean) * rstd * gv.y + bv.y);
    o.z = f2bf((v.z - mean) * rstd * gv.z + bv.z);
    o.w = f2bf((v.w - mean) * rstd * gv.w + bv.w);
    ((ushort4*)(y + (size_t)row * H))[tid] = o;
}

// ---------------- 128x128 GEMM (m97-style), used for Wo / FFN2 ----------------
// EPI: 0 = store bf16, 1 = gelu->bf16, 2 = f32 + resid
template <int EPI>
__global__ __launch_bounds__(256)
void gemm_kernel(const unsigned short* __restrict__ A, const unsigned short* __restrict__ Bt,
                 const float* __restrict__ bias, const float* __restrict__ resid,
                 void* __restrict__ outp, int M, int N, int K) {
    __shared__ __align__(16) unsigned short lA[128 * 32];
    __shared__ __align__(16) unsigned short lB[128 * 32];
    const int tid = threadIdx.x;
    const int lane = tid & 63, w = tid >> 6;
    const int wr = w >> 1, wc = w & 1;
    const int m0 = blockIdx.x * 128, n0 = blockIdx.y * 128;
    const int fr = lane & 15, fq = lane >> 4;
    f32x4 acc[4][4] = {};

    const int srow = (w * 2) * 16 + (lane >> 2);
    const int scol = (lane & 3) * 8;
    const size_t abase = (size_t)(m0 + srow) * K + scol;
    const size_t bbase = (size_t)(n0 + srow) * K + scol;
    unsigned short* lA0 = &lA[(w * 2) * 16 * 32];
    unsigned short* lB0 = &lB[(w * 2) * 16 * 32];

    for (int k0 = 0; k0 < K; k0 += 32) {
        gld16(A + abase + k0, lA0);
        gld16(A + abase + (size_t)16 * K + k0, lA0 + 16 * 32);
        gld16(Bt + bbase + k0, lB0);
        gld16(Bt + bbase + (size_t)16 * K + k0, lB0 + 16 * 32);
        __syncthreads();
        bf16x8 af[4], bfr[4];
#pragma unroll
        for (int m = 0; m < 4; ++m) af[m] = *(const bf16x8*)&lA[(wr * 64 + m * 16 + fr) * 32 + fq * 8];
#pragma unroll
        for (int n = 0; n < 4; ++n) bfr[n] = *(const bf16x8*)&lB[(wc * 64 + n * 16 + fr) * 32 + fq * 8];
#pragma unroll
        for (int m = 0; m < 4; ++m)
#pragma unroll
            for (int n = 0; n < 4; ++n)
                acc[m][n] = __builtin_amdgcn_mfma_f32_16x16x32_bf16(af[m], bfr[n], acc[m][n], 0, 0, 0);
        __syncthreads();
    }

#pragma unroll
    for (int m = 0; m < 4; ++m) {
        int row0 = m0 + wr * 64 + m * 16 + fq * 4;
#pragma unroll
        for (int n = 0; n < 4; ++n) {
            int col = n0 + wc * 64 + n * 16 + fr;
            float bz = bias[col];
#pragma unroll
            for (int j = 0; j < 4; ++j) {
                float vv = acc[m][n][j] + bz;
                size_t idx = (size_t)(row0 + j) * N + col;
                if (EPI == 0) {
                    ((unsigned short*)outp)[idx] = f2bf(vv);
                } else if (EPI == 1) {
                    float t = 0.5f * vv * (1.f + erff(vv * 0.70710678118654752f));
                    ((unsigned short*)outp)[idx] = f2bf(t);
                } else {
                    ((float*)outp)[idx] = vv + resid[idx];
                }
            }
        }
    }
}

// ---------------- 256x256 deep-pipelined GEMM (T2+T3+T4+T5), M fixed 8192 ----
// 4-deep LDS ring (4 x 32KB), BK=32, counted vmcnt (12/8/4/0), raw s_barrier.
// EPI: 0 = store bf16, 1 = gelu->bf16
template <int EPI>
__global__ __launch_bounds__(512)
void gemm256(const unsigned short* __restrict__ A, const unsigned short* __restrict__ Bt,
             const float* __restrict__ bias, void* __restrict__ outp, int N, int K) {
    __shared__ __align__(16) unsigned short lds[4][16384]; // per buf: A 16KB | B 16KB
    const int tid = threadIdx.x, lane = tid & 63, w = tid >> 6;
    const int wm = w >> 2, wn = w & 3;
    const int fr = lane & 15, fq = lane >> 4;

    // XCD-aware block swizzle (nwg % 8 == 0 for all our launches)
    const int nwg = gridDim.x;
    const int id = blockIdx.x;
    const int swz = (id & 7) * (nwg >> 3) + (id >> 3);
    const int m0 = (swz & 31) * 256, n0 = (swz >> 5) * 256;

    // staging source coords: LDS chunk idx -> (row, stored chunk); logical chunk
    // lc = sc ^ ((row>>1)&3), source k-offset = lc*8
    int rA[2], cA[2];
#pragma unroll
    for (int l = 0; l < 2; ++l) {
        int idx = l * 512 + tid;
        rA[l] = idx >> 2;
        cA[l] = ((idx & 3) ^ ((rA[l] >> 1) & 3)) * 8;
    }
    const int NT = K >> 5;

    auto stage = [&](int buf, int t) {
        const int k0 = t << 5;
        unsigned short* lb = &lds[buf][0];
#pragma unroll
        for (int l = 0; l < 2; ++l)
            gld16(A + (size_t)(m0 + rA[l]) * K + k0 + cA[l], lb + (size_t)(l * 512 + tid) * 8);
#pragma unroll
        for (int l = 0; l < 2; ++l)
            gld16(Bt + (size_t)(n0 + rA[l]) * K + k0 + cA[l], lb + 8192 + (size_t)(l * 512 + tid) * 8);
    };

    // fragment read byte offsets (swizzled): chunk = fq ^ ((row>>1)&3)
    int offA[8], offB[4];
#pragma unroll
    for (int mb = 0; mb < 8; ++mb) {
        int row = wm * 128 + mb * 16 + fr;
        offA[mb] = row * 64 + ((fq ^ (row >> 1)) & 3) * 16;
    }
#pragma unroll
    for (int nb = 0; nb < 4; ++nb) {
        int row = wn * 64 + nb * 16 + fr;
        offB[nb] = 16384 + row * 64 + ((fq ^ (row >> 1)) & 3) * 16;
    }

    f32x4 acc[8][4] = {};
#pragma unroll
    for (int p = 0; p < 3; ++p) stage(p, p);

    for (int t = 0; t < NT; ++t) {
        if (t + 3 < NT) stage((t + 3) & 3, t + 3);
        const int rem = NT - 1 - t;
        if (rem >= 3)      asm volatile("s_waitcnt vmcnt(12)" ::: "memory");
        else if (rem == 2) asm volatile("s_waitcnt vmcnt(8)" ::: "memory");
        else if (rem == 1) asm volatile("s_waitcnt vmcnt(4)" ::: "memory");
        else               asm volatile("s_waitcnt vmcnt(0)" ::: "memory");
        __builtin_amdgcn_s_barrier();
        __builtin_amdgcn_sched_barrier(0);
        const char* lb = (const char*)&lds[t & 3][0];
        bf16x8 aF[8], bF[4];
#pragma unroll
        for (int mb = 0; mb < 8; ++mb) aF[mb] = *(const bf16x8*)(lb + offA[mb]);
#pragma unroll
        for (int nb = 0; nb < 4; ++nb) bF[nb] = *(const bf16x8*)(lb + offB[nb]);
        __builtin_amdgcn_s_setprio(1);
#pragma unroll
        for (int mb = 0; mb < 8; ++mb)
#pragma unroll
            for (int nb = 0; nb < 4; ++nb)
                acc[mb][nb] = __builtin_amdgcn_mfma_f32_16x16x32_bf16(aF[mb], bF[nb], acc[mb][nb], 0, 0, 0);
        __builtin_amdgcn_s_setprio(0);
        __builtin_amdgcn_sched_barrier(0);
        __builtin_amdgcn_s_barrier();
    }

#pragma unroll
    for (int mb = 0; mb < 8; ++mb) {
        int row0 = m0 + wm * 128 + mb * 16 + fq * 4;
#pragma unroll
        for (int nb = 0; nb < 4; ++nb) {
            int col = n0 + wn * 64 + nb * 16 + fr;
            float bz = bias[col];
#pragma unroll
            for (int j = 0; j < 4; ++j) {
                float vv = acc[mb][nb][j] + bz;
                size_t idx = (size_t)(row0 + j) * N + col;
                if (EPI == 0) {
                    ((unsigned short*)outp)[idx] = f2bf(vv);
                } else {
                    float tg = 0.5f * vv * (1.f + erff(vv * 0.70710678118654752f));
                    ((unsigned short*)outp)[idx] = f2bf(tg);
                }
            }
        }
    }
}

// ---------------- flash attention with additive bias ----------------
__global__ __launch_bounds__(256)
void attn_kernel(const unsigned short* __restrict__ QKV, const float* __restrict__ bias,
                 unsigned short* __restrict__ O) {
    __shared__ __align__(16) unsigned short lK[2][4096];
    __shared__ __align__(16) unsigned short lV[2][4096];
    __shared__ __align__(16) unsigned short lP[4][16 * 64];
    const int tid = threadIdx.x, lane = tid & 63, w = tid >> 6;
    const int fr = lane & 15, fq = lane >> 4;
    const int b = blockIdx.x, h = blockIdx.y, q0 = blockIdx.z * 64;
    const size_t base = (size_t)b * S * QS + h * DK;
    const unsigned short* Qp = QKV + base;
    const unsigned short* Kp = QKV + base + H;
    const unsigned short* Vp = QKV + base + 2 * H;
    const size_t obase = (size_t)b * S * H + h * DK;

    bf16x8 aq[2];
    {
        const unsigned short* qp = Qp + (size_t)(q0 + w * 16 + fr) * QS + fq * 8;
        aq[0] = *(const bf16x8*)qp;
        aq[1] = *(const bf16x8*)(qp + 32);
    }

    const int chk0 = w * 128 + lane, chk1 = chk0 + 64;
    const int rK0 = chk0 >> 3, cK0 = ((chk0 & 7) ^ (rK0 & 7)) * 8;
    const int rK1 = chk1 >> 3, cK1 = ((chk1 & 7) ^ (rK1 & 7)) * 8;
    int vk0, vd0, vk1, vd1;
    {
        int ch = chk0;
        int dch = ch & 1, j = (ch >> 1) & 3, fqi = (ch >> 3) & 3, half = (ch >> 5) & 1,
            c = (ch >> 6) & 3, ks = (ch >> 8) & 1;
        vk0 = ks * 32 + fqi * 8 + half * 4 + j; vd0 = c * 16 + dch * 8;
        ch = chk1;
        dch = ch & 1; j = (ch >> 1) & 3; fqi = (ch >> 3) & 3; half = (ch >> 5) & 1;
        c = (ch >> 6) & 3; ks = (ch >> 8) & 1;
        vk1 = ks * 32 + fqi * 8 + half * 4 + j; vd1 = c * 16 + dch * 8;
    }

    f32x4 oacc[4] = {};
    float mrun[4], lrun[4];
#pragma unroll
    for (int j = 0; j < 4; ++j) { mrun[j] = -3e38f; lrun[j] = 0.f; }
    const float* bias_r[4];
#pragma unroll
    for (int j = 0; j < 4; ++j)
        bias_r[j] = bias + (size_t)h * S * S + (size_t)(q0 + w * 16 + fq * 4 + j) * S;

    auto stage = [&](int buf, int k0) {
        gld16(Kp + (size_t)(k0 + rK0) * QS + cK0, &lK[buf][w * 1024]);
        gld16(Kp + (size_t)(k0 + rK1) * QS + cK1, &lK[buf][w * 1024 + 512]);
        gld16(Vp + (size_t)(k0 + vk0) * QS + vd0, &lV[buf][w * 1024]);
        gld16(Vp + (size_t)(k0 + vk1) * QS + vd1, &lV[buf][w * 1024 + 512]);
    };

    stage(0, 0);
    int cur = 0;
    for (int kt = 0; kt < S / 64; ++kt) {
        const int k0 = kt * 64;
        __syncthreads();
        if (kt + 1 < S / 64) stage(cur ^ 1, k0 + 64);

        float bvreg[4][4];
#pragma unroll
        for (int c = 0; c < 4; ++c)
#pragma unroll
            for (int j = 0; j < 4; ++j) bvreg[c][j] = bias_r[j][k0 + c * 16 + fr];

        f32x4 sacc[4] = {};
        __builtin_amdgcn_s_setprio(1);
#pragma unroll
        for (int c = 0; c < 4; ++c) {
            int row = c * 16 + fr;
#pragma unroll
            for (int dh = 0; dh < 2; ++dh) {
                bf16x8 bk = *(const bf16x8*)((char*)lK[cur] +
                    ((row * 128 + dh * 64 + fq * 16) ^ ((row & 7) << 4)));
                sacc[c] = __builtin_amdgcn_mfma_f32_16x16x32_bf16(aq[dh], bk, sacc[c], 0, 0, 0);
            }
        }
        __builtin_amdgcn_s_setprio(0);

        float sb[4][4];
        float tmax[4] = {-3e38f, -3e38f, -3e38f, -3e38f};
#pragma unroll
        for (int c = 0; c < 4; ++c)
#pragma unroll
            for (int j = 0; j < 4; ++j) {
                float sv = sacc[c][j] * 0.125f + bvreg[c][j];
                sb[c][j] = sv;
                tmax[j] = fmaxf(tmax[j], sv);
            }
#pragma unroll
        for (int j = 0; j < 4; ++j)
#pragma unroll
            for (int m = 1; m < 16; m <<= 1) tmax[j] = fmaxf(tmax[j], __shfl_xor(tmax[j], m));
        float sf[4], rs[4];
#pragma unroll
        for (int j = 0; j < 4; ++j) {
            float mnew = fmaxf(mrun[j], tmax[j]);
            sf[j] = __expf(mrun[j] - mnew);
            mrun[j] = mnew;
            rs[j] = 0.f;
        }
#pragma unroll
        for (int c = 0; c < 4; ++c)
#pragma unroll
            for (int j = 0; j < 4; ++j) {
                float p = __expf(sb[c][j] - mrun[j]);
                rs[j] += p;
                int prow = fq * 4 + j;
                *(unsigned short*)((char*)&lP[w][0] +
                    ((prow * 128 + (c * 16 + fr) * 2) ^ ((prow & 7) << 4))) = f2bf(p);
            }
#pragma unroll
        for (int j = 0; j < 4; ++j) {
#pragma unroll
            for (int m = 1; m < 16; m <<= 1) rs[j] += __shfl_xor(rs[j], m);
            lrun[j] = lrun[j] * sf[j] + rs[j];
        }
#pragma unroll
        for (int c = 0; c < 4; ++c)
#pragma unroll
            for (int j = 0; j < 4; ++j) oacc[c][j] *= sf[j];

#pragma unroll
        for (int ks = 0; ks < 2; ++ks) {
            bf16x8 pa = *(const bf16x8*)((char*)&lP[w][0] +
                ((fr * 128 + ks * 64 + fq * 16) ^ ((fr & 7) << 4)));
            const char* vb8 = (const char*)lV[cur] + ks * 4096;
            u16x4 ra[4], rb[4];
#pragma unroll
            for (int c = 0; c < 4; ++c) {
                unsigned ad = (unsigned)(unsigned long long)(vb8 + c * 1024) + lane * 8;
                asm volatile("ds_read_b64_tr_b16 %0, %1" : "=&v"(ra[c]) : "v"(ad));
                asm volatile("ds_read_b64_tr_b16 %0, %1 offset:512" : "=&v"(rb[c]) : "v"(ad));
            }
            asm volatile("s_waitcnt lgkmcnt(0)" ::: "memory");
            __builtin_amdgcn_sched_barrier(0);
            __builtin_amdgcn_s_setprio(1);
#pragma unroll
            for (int c = 0; c < 4; ++c) {
                union { u16x4 h2[2]; bf16x8 v8; } u;
                u.h2[0] = ra[c]; u.h2[1] = rb[c];
                oacc[c] = __builtin_amdgcn_mfma_f32_16x16x32_bf16(pa, u.v8, oacc[c], 0, 0, 0);
            }
            __builtin_amdgcn_s_setprio(0);
        }
        cur ^= 1;
    }

#pragma unroll
    for (int c = 0; c < 4; ++c)
#pragma unroll
        for (int j = 0; j < 4; ++j) {
            int row = q0 + w * 16 + fq * 4 + j;
            int d = c * 16 + fr;
            O[obase + (size_t)row * H + d] = f2bf(oacc[c][j] / lrun[j]);
        }
}

extern "C" void kernel_launch(void* const* d_in, const int* in_sizes, int n_in,
                              void* d_out, int out_size, void* d_ws, size_t ws_size,
                              hipStream_t stream) {
    const float* x    = (const float*)d_in[0];
    const float* ab   = (const float*)d_in[1];
    const float* ln1g = (const float*)d_in[2];
    const float* ln1b = (const float*)d_in[3];
    const float* Wq   = (const float*)d_in[4];
    const float* bq   = (const float*)d_in[5];
    const float* Wk   = (const float*)d_in[6];
    const float* bk   = (const float*)d_in[7];
    const float* Wv   = (const float*)d_in[8];
    const float* bv   = (const float*)d_in[9];
    const float* Wo   = (const float*)d_in[10];
    const float* bo   = (const float*)d_in[11];
    const float* ln2g = (const float*)d_in[12];
    const float* ln2b = (const float*)d_in[13];
    const float* W1   = (const float*)d_in[14];
    const float* b1   = (const float*)d_in[15];
    const float* W2   = (const float*)d_in[16];
    const float* b2   = (const float*)d_in[17];

    char* ws = (char*)d_ws;
    size_t off = 0;
    auto alloc = [&](size_t bytes) -> void* {
        void* p = ws + off;
        off += (bytes + 255) & ~(size_t)255;
        return p;
    };
    unsigned short* Wqt = (unsigned short*)alloc((size_t)H * H * 2); // contiguous q,k,v
    unsigned short* Wkt = (unsigned short*)alloc((size_t)H * H * 2);
    unsigned short* Wvt = (unsigned short*)alloc((size_t)H * H * 2);
    unsigned short* Wot = (unsigned short*)alloc((size_t)H * H * 2);
    unsigned short* W1t = (unsigned short*)alloc((size_t)H * FF * 2);
    unsigned short* W2t = (unsigned short*)alloc((size_t)H * FF * 2);
    float* bqkv        = (float*)alloc((size_t)QS * 4);
    unsigned short* ybuf = (unsigned short*)alloc((size_t)Mrows * H * 2);
    unsigned short* qkvb = (unsigned short*)alloc((size_t)Mrows * QS * 2);
    unsigned short* ob = (unsigned short*)alloc((size_t)Mrows * H * 2);
    unsigned short* hb = (unsigned short*)alloc((size_t)Mrows * FF * 2);
    (void)ws_size; (void)in_sizes; (void)n_in; (void)out_size;

    dim3 tb(32, 8, 1);
    wcvt<<<dim3(H / 32, H / 32), tb, 0, stream>>>(Wq, Wqt, H, H);
    wcvt<<<dim3(H / 32, H / 32), tb, 0, stream>>>(Wk, Wkt, H, H);
    wcvt<<<dim3(H / 32, H / 32), tb, 0, stream>>>(Wv, Wvt, H, H);
    wcvt<<<dim3(H / 32, H / 32), tb, 0, stream>>>(Wo, Wot, H, H);
    wcvt<<<dim3(FF / 32, H / 32), tb, 0, stream>>>(W1, W1t, H, FF);
    wcvt<<<dim3(H / 32, FF / 32), tb, 0, stream>>>(W2, W2t, FF, H);
    catbias<<<QS / 256, 256, 0, stream>>>(bq, bk, bv, bqkv);

    ln_kernel<<<Mrows, 256, 0, stream>>>(x, ln1g, ln1b, ybuf);

    // fused QKV projection: [8192,1024] @ [1024,3072] — 256^2 pipelined kernel
    gemm256<0><<<dim3((Mrows / 256) * (QS / 256)), 512, 0, stream>>>(ybuf, Wqt, bqkv, qkvb, QS, H);

    attn_kernel<<<dim3(Bb, NH, S / 64), 256, 0, stream>>>(qkvb, ab, ob);

    gemm_kernel<2><<<dim3(Mrows / 128, H / 128), 256, 0, stream>>>(ob, Wot, bo, x, d_out, Mrows, H, H);

    ln_kernel<<<Mrows, 256, 0, stream>>>((const float*)d_out, ln2g, ln2b, ybuf);

    // FFN1: [8192,1024] @ [1024,4096] + gelu — 256^2 pipelined kernel
    gemm256<1><<<dim3((Mrows / 256) * (FF / 256)), 512, 0, stream>>>(ybuf, W1t, b1, hb, FF, H);

    gemm_kernel<2><<<dim3(Mrows / 128, H / 128), 256, 0, stream>>>(hb, W2t, b2, (const float*)d_out, d_out, Mrows, H, FF);
}